// Round 14
// baseline (227.696 us; speedup 1.0000x reference)
//
#include <hip/hip_runtime.h>
#include <hip/hip_bf16.h>
#include <math.h>

#define NN 8
#define CH 128
#define HH 36
#define WWI 36
#define PP 1296      // 36*36
#define DD 1156      // 34*34
#define VP 1280      // vb row pitch (shorts) — covers d-tail fragment reads
#define KC 1152      // 128*9
#define QT 81        // q tiles of 16
#define DT 10        // d tiles of 128

typedef __attribute__((ext_vector_type(8))) short short8;
typedef __attribute__((ext_vector_type(4))) float f32x4;

__device__ inline unsigned short f2bf(float f) {
    __hip_bfloat16 h = __float2bfloat16(f);
    return __builtin_bit_cast(unsigned short, h);
}
__device__ inline float fast_tanh(float x) {
    float e = __expf(2.f * x);
    return 1.f - 2.f / (e + 1.f);
}
#define MFMA(a, b, c) __builtin_amdgcn_mfma_f32_16x16x32_bf16((a), (b), (c), 0, 0, 0)

// ---------------------------------------------------------------------------
// setup: weight cast/reorder + folded constants (identical to round 13).
// ---------------------------------------------------------------------------
__global__ void k_setup(const float* __restrict__ wq, const float* __restrict__ wk,
                        const float* __restrict__ wv, const float* __restrict__ wh,
                        const float* __restrict__ wo, const float* __restrict__ wx,
                        const float* __restrict__ c0, const float* __restrict__ w_vc,
                        const float* __restrict__ b_h,
                        unsigned short* __restrict__ wcat, unsigned short* __restrict__ whb,
                        unsigned short* __restrict__ wob, unsigned short* __restrict__ wxb,
                        float* __restrict__ hconst)
{
    if (blockIdx.x == 576) {
        __shared__ float vc[CH];
        int c = threadIdx.x;
        if (c < CH) {
            float s = 0.f;
            for (int ci = 0; ci < CH; ++ci) {
                const float* wp = w_vc + ((size_t)c * CH + ci) * 9;
                float ws = 0.f;
#pragma unroll
                for (int k = 0; k < 9; ++k) ws += wp[k];
                s += c0[ci] * ws;
            }
            vc[c] = s;
        }
        __syncthreads();
        if (c < CH) {
            float hs = b_h[c];
            for (int ci = 0; ci < CH; ++ci) hs += wh[(size_t)c * 384 + 256 + ci] * vc[ci];
            hconst[c] = hs;
        }
        return;
    }
    int t = blockIdx.x * 256 + threadIdx.x;    // 0..147455
    int co = t / KC;
    int rem = t - co * KC;
    int tap = rem >> 7, ci = rem & 127;
    int iidx = co * KC + ci * 9 + tap;
    wcat[t] = f2bf(wq[iidx]);
    wcat[147456 + t] = f2bf(wk[iidx]);
    wcat[294912 + t] = f2bf(wv[iidx]);
    if (t < 32768) {
        int c2 = t >> 8, k2 = t & 255;
        whb[t] = f2bf(wh[c2 * 384 + k2]);
    }
    if (t < 16384) { wob[t] = f2bf(wo[t]); wxb[t] = f2bf(wx[t]); }
}

// ---------------------------------------------------------------------------
// proj — identical to round 13.
// ---------------------------------------------------------------------------
__global__ __launch_bounds__(64)
void k_proj(const float* __restrict__ inp, const unsigned short* __restrict__ wxb,
            const float* __restrict__ bx, unsigned short* __restrict__ xt)
{
    const int lane = threadIdx.x;
    const int quad = lane >> 4, lrow = lane & 15;
    const int p0 = blockIdx.x * 16;
    const int co0 = blockIdx.y * 64;
    const int n = blockIdx.z;
    const float* in_n = inp + (size_t)n * CH * PP;
    f32x4 acc[4] = {};

#pragma unroll
    for (int ks = 0; ks < 4; ++ks) {
        union { short8 v; unsigned short u[8]; } a;
        int ci0 = ks * 32 + quad * 8;
#pragma unroll
        for (int j = 0; j < 8; ++j)
            a.u[j] = f2bf(in_n[(size_t)(ci0 + j) * PP + p0 + lrow]);
#pragma unroll
        for (int ni = 0; ni < 4; ++ni) {
            short8 b = *(const short8*)&wxb[(size_t)(co0 + ni * 16 + lrow) * CH + ks * 32 + quad * 8];
            acc[ni] = MFMA(a.v, b, acc[ni]);
        }
    }
    unsigned short* xn = xt + (size_t)n * PP * CH;
#pragma unroll
    for (int ni = 0; ni < 4; ++ni) {
        float bv = bx[co0 + ni * 16 + lrow];
#pragma unroll
        for (int r = 0; r < 4; ++r)
            xn[(size_t)(p0 + quad * 4 + r) * CH + co0 + ni * 16 + lrow] = f2bf(acc[ni][r] + bv);
    }
}

// ---------------------------------------------------------------------------
// fused q/k/v conv, LDS-staged, co-split for occupancy. Block = 4 waves on a
// (64 tokens x 64 co) tile; blockIdx.y in 0..5: mode = y>>1 (0=q SAME, 1=k,
// 2=v), co group = (y&1)*64. K staged in 18 chunks of 64 (2 sub-chunks of 32,
// pitch-40 regions), double-buffered: prefetch chunk kc+1's 4 uint4/thread
// while MFMAing chunk kc. Wave w owns co-slice w (16 rows). LDS 40,960 B ->
// exactly 4 blocks/CU; grid (21, 6, 8) = 1008 blocks ~ fully co-resident.
// ---------------------------------------------------------------------------
__global__ __launch_bounds__(256)
void k_conv(const unsigned short* __restrict__ xt, const unsigned short* __restrict__ wcat,
            unsigned short* __restrict__ qt, unsigned short* __restrict__ kt,
            unsigned short* __restrict__ vb)
{
    __shared__ unsigned short lA[2][2][64 * 40];   // [buf][sub][row*40+k]
    __shared__ unsigned short lB[2][2][64 * 40];
    const int t = threadIdx.x;
    const int wave = t >> 6, lane = t & 63;
    const int quad = lane >> 4, lrow = lane & 15;
    const int y = blockIdx.y;                 // 0..5
    const int mode = y >> 1;                  // 0=q(SAME), 1=k, 2=v
    const int cog = y & 1;
    const int n = blockIdx.z;
    const int limit = (mode == 0) ? PP : DD;
    const int tile0 = blockIdx.x * 64;
    if (tile0 >= limit) return;               // block-uniform exit
    const unsigned short* xn = xt + (size_t)n * PP * CH;
    const unsigned short* wb = wcat + (size_t)(mode * 128 + cog * 64) * KC;

    const int arow = t >> 2, aseg = t & 3;
    int apr, apc;
    {
        int tok = tile0 + arow; if (tok >= limit) tok = limit - 1;
        int dv = (mode == 0) ? 36 : 34;
        apr = tok / dv; apc = tok - apr * dv;
    }

    uint4 ra[2], rb[2];
    auto loadChunk = [&](int kc) {            // kc in 0..17, k base = kc*64
#pragma unroll
        for (int sub = 0; sub < 2; ++sub) {
            int ks = kc * 2 + sub;            // 32-k sub-chunk index 0..35
            int tap = ks >> 2;
            int ky = tap / 3, kx = tap - ky * 3;
            int ci = (ks & 3) * 32 + aseg * 8;
            if (mode == 0) {
                int yy = apr + ky - 1, xx = apc + kx - 1;
                bool ok = (yy >= 0) && (yy < HH) && (xx >= 0) && (xx < WWI);
                ra[sub] = make_uint4(0, 0, 0, 0);
                if (ok) ra[sub] = *(const uint4*)&xn[(size_t)(yy * WWI + xx) * CH + ci];
            } else {
                ra[sub] = *(const uint4*)&xn[(size_t)((apr + ky) * WWI + apc + kx) * CH + ci];
            }
            rb[sub] = *(const uint4*)&wb[(size_t)arow * KC + ks * 32 + aseg * 8];
        }
    };
    auto storeChunk = [&](int buf) {
#pragma unroll
        for (int sub = 0; sub < 2; ++sub) {
            *(uint4*)&lA[buf][sub][arow * 40 + aseg * 8] = ra[sub];
            *(uint4*)&lB[buf][sub][arow * 40 + aseg * 8] = rb[sub];
        }
    };

    f32x4 acc[4] = {};
    loadChunk(0);
    storeChunk(0);
    __syncthreads();

#pragma unroll
    for (int kc = 0; kc < 18; ++kc) {
        const int buf = kc & 1;
        if (kc < 17) loadChunk(kc + 1);       // in flight during compute
#pragma unroll
        for (int sub = 0; sub < 2; ++sub) {
            short8 b = *(const short8*)&lB[buf][sub][(wave * 16 + lrow) * 40 + quad * 8];
#pragma unroll
            for (int mi = 0; mi < 4; ++mi) {
                short8 a = *(const short8*)&lA[buf][sub][(mi * 16 + lrow) * 40 + quad * 8];
                acc[mi] = MFMA(a, b, acc[mi]);
            }
        }
        if (kc < 17) storeChunk(buf ^ 1);     // vmcnt wait lands here
        __syncthreads();
    }

    const int co = cog * 64 + wave * 16 + lrow;
    if (mode == 0) {
        unsigned short* qn = qt + (size_t)n * PP * CH;
#pragma unroll
        for (int mi = 0; mi < 4; ++mi)
#pragma unroll
            for (int r = 0; r < 4; ++r) {
                int p = tile0 + mi * 16 + quad * 4 + r;
                if (p < PP) qn[(size_t)p * CH + co] = f2bf(acc[mi][r]);
            }
    } else if (mode == 1) {
        unsigned short* kn = kt + (size_t)n * DD * CH;
#pragma unroll
        for (int mi = 0; mi < 4; ++mi)
#pragma unroll
            for (int r = 0; r < 4; ++r) {
                int d = tile0 + mi * 16 + quad * 4 + r;
                if (d < DD) kn[(size_t)d * CH + co] = f2bf(acc[mi][r]);
            }
    } else {
        unsigned short* vn = vb + (size_t)n * CH * VP;
#pragma unroll
        for (int mi = 0; mi < 4; ++mi)
#pragma unroll
            for (int r = 0; r < 4; ++r) {
                int d = tile0 + mi * 16 + quad * 4 + r;
                if (d < DD) vn[(size_t)co * VP + d] = f2bf(acc[mi][r]);
            }
    }
}

// ---------------------------------------------------------------------------
// partial attention, LDS-staged — identical to round 13.
// ---------------------------------------------------------------------------
__global__ __launch_bounds__(256)
void k_attn(const unsigned short* __restrict__ qt, const unsigned short* __restrict__ kt,
            const unsigned short* __restrict__ vb, _Float16* __restrict__ po,
            float* __restrict__ pm, float* __restrict__ pl)
{
    __shared__ unsigned short lS[2][128 * 40];    // 2 x 10240 B chunk staging
    __shared__ unsigned short lp[4][16 * 136];    // per-wave P transpose
    const int t = threadIdx.x;
    const int wave = t >> 6, lane = t & 63;
    const int quad = lane >> 4, lrow = lane & 15;
    const int qg = blockIdx.x;
    const int dt = blockIdx.y;
    const int n = blockIdx.z;
    const int qti = qg * 4 + wave;                // may be >= QT (tail)
    const int d0 = dt * 128;
    const unsigned short* qn = qt + (size_t)n * PP * CH;
    const unsigned short* kn = kt + (size_t)n * DD * CH;
    const unsigned short* vn = vb + (size_t)n * CH * VP;

    const int arow = t >> 2, aseg8 = (t & 3) * 8;
    int kr0 = d0 + arow;      if (kr0 >= DD) kr0 = DD - 1;
    int kr1 = d0 + arow + 64; if (kr1 >= DD) kr1 = DD - 1;
    const unsigned short* kp0 = kn + (size_t)kr0 * CH + aseg8;
    const unsigned short* kp1 = kn + (size_t)kr1 * CH + aseg8;
    const unsigned short* vp0 = vn + (size_t)arow * VP + d0 + aseg8;
    const unsigned short* vp1 = vn + (size_t)(arow + 64) * VP + d0 + aseg8;
    const int lo0 = arow * 40 + aseg8;
    const int lo1 = (arow + 64) * 40 + aseg8;

    short8 qa[4];
    {
        int qrow = qti * 16 + lrow; if (qrow >= PP) qrow = PP - 1;
#pragma unroll
        for (int ks = 0; ks < 4; ++ks)
            qa[ks] = *(const short8*)&qn[(size_t)qrow * CH + ks * 32 + quad * 8];
    }

    // ---- S = Q.K^T, chunked over c, double-buffered ----
    f32x4 s[8] = {};
    uint4 r0 = *(const uint4*)kp0;
    uint4 r1 = *(const uint4*)kp1;
    *(uint4*)&lS[0][lo0] = r0;
    *(uint4*)&lS[0][lo1] = r1;
    __syncthreads();
#pragma unroll
    for (int ks = 0; ks < 4; ++ks) {
        const int buf = ks & 1;
        if (ks < 3) {
            r0 = *(const uint4*)(kp0 + (ks + 1) * 32);
            r1 = *(const uint4*)(kp1 + (ks + 1) * 32);
        }
#pragma unroll
        for (int ni = 0; ni < 8; ++ni) {
            short8 b = *(const short8*)&lS[buf][(ni * 16 + lrow) * 40 + quad * 8];
            s[ni] = MFMA(qa[ks], b, s[ni]);
        }
        if (ks < 3) {
            *(uint4*)&lS[buf ^ 1][lo0] = r0;
            *(uint4*)&lS[buf ^ 1][lo1] = r1;
        }
        __syncthreads();
    }

    // ---- tail mask + partial softmax (per wave) ----
#pragma unroll
    for (int ni = 0; ni < 8; ++ni)
        if (d0 + ni * 16 + lrow >= DD)
#pragma unroll
            for (int r = 0; r < 4; ++r) s[ni][r] = -1e30f;

    float mx[4] = {-1e30f, -1e30f, -1e30f, -1e30f};
#pragma unroll
    for (int ni = 0; ni < 8; ++ni)
#pragma unroll
        for (int r = 0; r < 4; ++r) mx[r] = fmaxf(mx[r], s[ni][r]);
#pragma unroll
    for (int off = 1; off < 16; off <<= 1)
#pragma unroll
        for (int r = 0; r < 4; ++r) mx[r] = fmaxf(mx[r], __shfl_xor(mx[r], off, 64));

    float rs[4] = {0.f, 0.f, 0.f, 0.f};
#pragma unroll
    for (int ni = 0; ni < 8; ++ni)
#pragma unroll
        for (int r = 0; r < 4; ++r) {
            float e = __expf(s[ni][r] - mx[r]);
            s[ni][r] = e;
            rs[r] += e;
        }
#pragma unroll
    for (int off = 1; off < 16; off <<= 1)
#pragma unroll
        for (int r = 0; r < 4; ++r) rs[r] += __shfl_xor(rs[r], off, 64);

    // P -> wave-private LDS (C-layout -> A-layout transpose)
#pragma unroll
    for (int ni = 0; ni < 8; ++ni)
#pragma unroll
        for (int r = 0; r < 4; ++r)
            lp[wave][(quad * 4 + r) * 136 + ni * 16 + lrow] = f2bf(s[ni][r]);

    // ---- O = P.V, chunked over d ----
    f32x4 o[8] = {};
    r0 = *(const uint4*)vp0;
    r1 = *(const uint4*)vp1;
    *(uint4*)&lS[0][lo0] = r0;
    *(uint4*)&lS[0][lo1] = r1;
    __syncthreads();
#pragma unroll
    for (int ks = 0; ks < 4; ++ks) {
        const int buf = ks & 1;
        if (ks < 3) {
            r0 = *(const uint4*)(vp0 + (ks + 1) * 32);
            r1 = *(const uint4*)(vp1 + (ks + 1) * 32);
        }
        short8 pa = *(const short8*)&lp[wave][lrow * 136 + ks * 32 + quad * 8];
#pragma unroll
        for (int ni = 0; ni < 8; ++ni) {
            short8 b = *(const short8*)&lS[buf][(ni * 16 + lrow) * 40 + quad * 8];
            o[ni] = MFMA(pa, b, o[ni]);
        }
        if (ks < 3) {
            *(uint4*)&lS[buf ^ 1][lo0] = r0;
            *(uint4*)&lS[buf ^ 1][lo1] = r1;
        }
        __syncthreads();
    }

    if (qti < QT) {
        const int base = (n * QT + qti) * DT + dt;
        _Float16* pob = po + (size_t)base * 2048;
#pragma unroll
        for (int ni = 0; ni < 8; ++ni)
#pragma unroll
            for (int r = 0; r < 4; ++r)
                pob[(quad * 4 + r) * 128 + ni * 16 + lrow] = (_Float16)o[ni][r];
        if (lrow == 0)
#pragma unroll
            for (int r = 0; r < 4; ++r) {
                pm[base * 16 + quad * 4 + r] = mx[r];
                pl[base * 16 + quad * 4 + r] = rs[r];
            }
    }
}

// ---------------------------------------------------------------------------
// attention reduce — identical to round 13.
// ---------------------------------------------------------------------------
__global__ __launch_bounds__(256)
void k_ared(const _Float16* __restrict__ po, const float* __restrict__ pm,
            const float* __restrict__ pl, unsigned short* __restrict__ a0t)
{
    __shared__ float sm[160], ssc[160], smg[16], sli[16];
    const int qti = blockIdx.x;
    const int n = blockIdx.y;
    const int base = (n * QT + qti) * DT;
    const int t = threadIdx.x;
    if (t < 160) sm[t] = pm[base * 16 + t];
    __syncthreads();
    if (t < 16) {
        float mg = -1e30f;
#pragma unroll
        for (int dt = 0; dt < DT; ++dt) mg = fmaxf(mg, sm[dt * 16 + t]);
        float ls = 0.f;
#pragma unroll
        for (int dt = 0; dt < DT; ++dt) ls += __expf(sm[dt * 16 + t] - mg) * pl[base * 16 + dt * 16 + t];
        smg[t] = mg; sli[t] = 1.f / ls;
    }
    __syncthreads();
    if (t < 160) ssc[t] = __expf(sm[t] - smg[t & 15]);
    __syncthreads();

    unsigned short* an = a0t + (size_t)n * PP * CH;
#pragma unroll
    for (int k = 0; k < 8; ++k) {
        int idx = t + k * 256;
        int row = idx >> 7, c = idx & 127;
        float acc = 0.f;
#pragma unroll
        for (int dt = 0; dt < DT; ++dt)
            acc += ssc[dt * 16 + row] * (float)po[(size_t)(base + dt) * 2048 + idx];
        an[(size_t)(qti * 16 + row) * CH + c] = f2bf(acc * sli[row]);
    }
}

// ---------------------------------------------------------------------------
// fused h+out — identical to round 13.
// ---------------------------------------------------------------------------
__global__ __launch_bounds__(256)
void k_hout(const unsigned short* __restrict__ xt, const unsigned short* __restrict__ a0t,
            const unsigned short* __restrict__ whb, const float* __restrict__ hconst,
            const unsigned short* __restrict__ wob, const float* __restrict__ bo,
            float* __restrict__ out)
{
    __shared__ unsigned short lh[16 * 136];
    const int t = threadIdx.x;
    const int wave = t >> 6, lane = t & 63;
    const int quad = lane >> 4, lrow = lane & 15;
    const int p0 = blockIdx.x * 16;
    const int n = blockIdx.y;
    const unsigned short* x0 = xt + (size_t)n * PP * CH;
    const unsigned short* a0 = a0t + (size_t)n * PP * CH;

    f32x4 acc[2] = {};
#pragma unroll
    for (int ks = 0; ks < 8; ++ks) {
        int col = (ks & 3) * 32 + quad * 8;
        const unsigned short* src = (ks < 4) ? x0 : a0;
        short8 a = *(const short8*)&src[(size_t)(p0 + lrow) * CH + col];
#pragma unroll
        for (int j = 0; j < 2; ++j) {
            int ni = wave * 2 + j;
            short8 b = *(const short8*)&whb[(size_t)(ni * 16 + lrow) * 256 + ks * 32 + quad * 8];
            acc[j] = MFMA(a, b, acc[j]);
        }
    }
#pragma unroll
    for (int j = 0; j < 2; ++j) {
        int ni = wave * 2 + j;
        float hc = hconst[ni * 16 + lrow];
#pragma unroll
        for (int r = 0; r < 4; ++r)
            lh[(quad * 4 + r) * 136 + ni * 16 + lrow] = f2bf(fast_tanh(acc[j][r] + hc));
    }
    __syncthreads();

    f32x4 acc2[2] = {};
#pragma unroll
    for (int ks = 0; ks < 4; ++ks) {
        short8 a = *(const short8*)&lh[lrow * 136 + ks * 32 + quad * 8];
#pragma unroll
        for (int j = 0; j < 2; ++j) {
            int ni = wave * 2 + j;
            short8 b = *(const short8*)&wob[(size_t)(ni * 16 + lrow) * CH + ks * 32 + quad * 8];
            acc2[j] = MFMA(a, b, acc2[j]);
        }
    }
#pragma unroll
    for (int j = 0; j < 2; ++j) {
        int ni = wave * 2 + j;
        float bv = bo[ni * 16 + lrow];
#pragma unroll
        for (int r = 0; r < 4; ++r)
            out[((size_t)(n * CH + ni * 16 + lrow)) * PP + p0 + quad * 4 + r] = acc2[j][r] + bv;
    }
}

// ---------------------------------------------------------------------------
extern "C" void kernel_launch(void* const* d_in, const int* in_sizes, int n_in,
                              void* d_out, int out_size, void* d_ws, size_t ws_size,
                              hipStream_t stream)
{
    const float* inp  = (const float*)d_in[0];
    const float* c0   = (const float*)d_in[1];
    const float* w_x  = (const float*)d_in[2];
    const float* b_x  = (const float*)d_in[3];
    const float* w_qx = (const float*)d_in[4];
    const float* w_kx = (const float*)d_in[6];
    const float* w_vx = (const float*)d_in[8];
    const float* w_vc = (const float*)d_in[9];
    const float* w_h  = (const float*)d_in[14];
    const float* b_h  = (const float*)d_in[15];
    const float* w_o  = (const float*)d_in[16];
    const float* b_o  = (const float*)d_in[17];
    float* out = (float*)d_out;

    char* w = (char*)d_ws;
    unsigned short* xt   = (unsigned short*)(w);             // 2,654,208
    unsigned short* qt   = (unsigned short*)(w + 2654208);   // 2,654,208
    unsigned short* kt   = (unsigned short*)(w + 5308416);   // 2,367,488
    unsigned short* vb   = (unsigned short*)(w + 7675904);   // 2,621,440
    unsigned short* a0t  = (unsigned short*)(w + 10297344);  // 2,654,208
    unsigned short* wcat = (unsigned short*)(w + 12951552);  // 884,736
    unsigned short* wxb  = (unsigned short*)(w + 13836288);  // 32,768
    unsigned short* whb  = (unsigned short*)(w + 13869056);  // 65,536
    unsigned short* wob  = (unsigned short*)(w + 13934592);  // 32,768
    float* hconst        = (float*)(w + 13967360);           // 512
    float* pm            = (float*)(w + 13967872);           // 414,720
    float* pl            = (float*)(w + 14382592);           // 414,720
    _Float16* po         = (_Float16*)(w + 14797312);        // 26,542,080 -> 41.3 MB total

    hipLaunchKernelGGL(k_setup, dim3(577), dim3(256), 0, stream,
                       w_qx, w_kx, w_vx, w_h, w_o, w_x, c0, w_vc, b_h,
                       wcat, whb, wob, wxb, hconst);

    hipLaunchKernelGGL(k_proj, dim3(QT, 2, NN), dim3(64), 0, stream, inp, wxb, b_x, xt);

    hipLaunchKernelGGL(k_conv, dim3(21, 6, NN), dim3(256), 0, stream, xt, wcat, qt, kt, vb);

    hipLaunchKernelGGL(k_attn, dim3(21, DT, NN), dim3(256), 0, stream, qt, kt, vb, po, pm, pl);
    hipLaunchKernelGGL(k_ared, dim3(QT, NN), dim3(256), 0, stream, po, pm, pl, a0t);

    hipLaunchKernelGGL(k_hout, dim3(QT, NN), dim3(256), 0, stream,
                       xt, a0t, whb, hconst, wob, b_o, out);
}

// Round 15
// 199.212 us; speedup vs baseline: 1.1430x; 1.1430x over previous
//
#include <hip/hip_runtime.h>
#include <hip/hip_bf16.h>
#include <math.h>

#define NN 8
#define CH 128
#define HH 36
#define WWI 36
#define PP 1296      // 36*36
#define DD 1156      // 34*34
#define VP 1280      // vb row pitch (shorts) — covers d-tail fragment reads
#define KC 1152      // 128*9
#define QT 81        // q tiles of 16
#define DT 10        // d tiles of 128

typedef __attribute__((ext_vector_type(8))) short short8;
typedef __attribute__((ext_vector_type(4))) float f32x4;

__device__ inline unsigned short f2bf(float f) {
    __hip_bfloat16 h = __float2bfloat16(f);
    return __builtin_bit_cast(unsigned short, h);
}
__device__ inline float fast_tanh(float x) {
    float e = __expf(2.f * x);
    return 1.f - 2.f / (e + 1.f);
}
#define MFMA(a, b, c) __builtin_amdgcn_mfma_f32_16x16x32_bf16((a), (b), (c), 0, 0, 0)

// ---------------------------------------------------------------------------
// setup: weight cast/reorder + folded constants (identical to round 13).
// ---------------------------------------------------------------------------
__global__ void k_setup(const float* __restrict__ wq, const float* __restrict__ wk,
                        const float* __restrict__ wv, const float* __restrict__ wh,
                        const float* __restrict__ wo, const float* __restrict__ wx,
                        const float* __restrict__ c0, const float* __restrict__ w_vc,
                        const float* __restrict__ b_h,
                        unsigned short* __restrict__ wcat, unsigned short* __restrict__ whb,
                        unsigned short* __restrict__ wob, unsigned short* __restrict__ wxb,
                        float* __restrict__ hconst)
{
    if (blockIdx.x == 576) {
        __shared__ float vc[CH];
        int c = threadIdx.x;
        if (c < CH) {
            float s = 0.f;
            for (int ci = 0; ci < CH; ++ci) {
                const float* wp = w_vc + ((size_t)c * CH + ci) * 9;
                float ws = 0.f;
#pragma unroll
                for (int k = 0; k < 9; ++k) ws += wp[k];
                s += c0[ci] * ws;
            }
            vc[c] = s;
        }
        __syncthreads();
        if (c < CH) {
            float hs = b_h[c];
            for (int ci = 0; ci < CH; ++ci) hs += wh[(size_t)c * 384 + 256 + ci] * vc[ci];
            hconst[c] = hs;
        }
        return;
    }
    int t = blockIdx.x * 256 + threadIdx.x;    // 0..147455
    int co = t / KC;
    int rem = t - co * KC;
    int tap = rem >> 7, ci = rem & 127;
    int iidx = co * KC + ci * 9 + tap;
    wcat[t] = f2bf(wq[iidx]);
    wcat[147456 + t] = f2bf(wk[iidx]);
    wcat[294912 + t] = f2bf(wv[iidx]);
    if (t < 32768) {
        int c2 = t >> 8, k2 = t & 255;
        whb[t] = f2bf(wh[c2 * 384 + k2]);
    }
    if (t < 16384) { wob[t] = f2bf(wo[t]); wxb[t] = f2bf(wx[t]); }
}

// ---------------------------------------------------------------------------
// proj — identical to round 13.
// ---------------------------------------------------------------------------
__global__ __launch_bounds__(64)
void k_proj(const float* __restrict__ inp, const unsigned short* __restrict__ wxb,
            const float* __restrict__ bx, unsigned short* __restrict__ xt)
{
    const int lane = threadIdx.x;
    const int quad = lane >> 4, lrow = lane & 15;
    const int p0 = blockIdx.x * 16;
    const int co0 = blockIdx.y * 64;
    const int n = blockIdx.z;
    const float* in_n = inp + (size_t)n * CH * PP;
    f32x4 acc[4] = {};

#pragma unroll
    for (int ks = 0; ks < 4; ++ks) {
        union { short8 v; unsigned short u[8]; } a;
        int ci0 = ks * 32 + quad * 8;
#pragma unroll
        for (int j = 0; j < 8; ++j)
            a.u[j] = f2bf(in_n[(size_t)(ci0 + j) * PP + p0 + lrow]);
#pragma unroll
        for (int ni = 0; ni < 4; ++ni) {
            short8 b = *(const short8*)&wxb[(size_t)(co0 + ni * 16 + lrow) * CH + ks * 32 + quad * 8];
            acc[ni] = MFMA(a.v, b, acc[ni]);
        }
    }
    unsigned short* xn = xt + (size_t)n * PP * CH;
#pragma unroll
    for (int ni = 0; ni < 4; ++ni) {
        float bv = bx[co0 + ni * 16 + lrow];
#pragma unroll
        for (int r = 0; r < 4; ++r)
            xn[(size_t)(p0 + quad * 4 + r) * CH + co0 + ni * 16 + lrow] = f2bf(acc[ni][r] + bv);
    }
}

// ---------------------------------------------------------------------------
// fused q/k/v conv — ROUND-13 VERSION (reverted: the R14 co-split exploded
// WRITE_SIZE 7.2->68 MB via split-cacheline L2 thrash). Block = 4 waves,
// tile 64 tokens x 128 co, K=1152 in 36 chunks of 32, double-buffered LDS.
// ---------------------------------------------------------------------------
__global__ __launch_bounds__(256)
void k_conv(const unsigned short* __restrict__ xt, const unsigned short* __restrict__ wcat,
            unsigned short* __restrict__ qt, unsigned short* __restrict__ kt,
            unsigned short* __restrict__ vb)
{
    __shared__ unsigned short lA[2][64 * 40];     // 2 x 5120 B
    __shared__ unsigned short lB[2][128 * 40];    // 2 x 10240 B
    const int t = threadIdx.x;
    const int wave = t >> 6, lane = t & 63;
    const int quad = lane >> 4, lrow = lane & 15;
    const int mode = blockIdx.y;
    const int n = blockIdx.z;
    const int limit = (mode == 0) ? PP : DD;
    const int tile0 = blockIdx.x * 64;
    if (tile0 >= limit) return;
    const unsigned short* xn = xt + (size_t)n * PP * CH;
    const unsigned short* wb = wcat + (size_t)mode * 128 * KC;

    const int arow = t >> 2, aseg = t & 3;
    int apr, apc;
    {
        int tok = tile0 + arow; if (tok >= limit) tok = limit - 1;
        int dv = (mode == 0) ? 36 : 34;
        apr = tok / dv; apc = tok - apr * dv;
    }

    uint4 ra, rb0, rb1;
    auto loadChunk = [&](int ks) {
        int tap = ks >> 2;
        int ky = tap / 3, kx = tap - ky * 3;
        int ci = (ks & 3) * 32 + aseg * 8;
        if (mode == 0) {
            int yy = apr + ky - 1, xx = apc + kx - 1;
            bool ok = (yy >= 0) && (yy < HH) && (xx >= 0) && (xx < WWI);
            ra = make_uint4(0, 0, 0, 0);
            if (ok) ra = *(const uint4*)&xn[(size_t)(yy * WWI + xx) * CH + ci];
        } else {
            int yy = apr + ky, xx = apc + kx;
            ra = *(const uint4*)&xn[(size_t)(yy * WWI + xx) * CH + ci];
        }
        rb0 = *(const uint4*)&wb[(size_t)arow * KC + ks * 32 + aseg * 8];
        rb1 = *(const uint4*)&wb[(size_t)(arow + 64) * KC + ks * 32 + aseg * 8];
    };
    auto storeChunk = [&](int buf) {
        *(uint4*)&lA[buf][arow * 40 + aseg * 8] = ra;
        *(uint4*)&lB[buf][arow * 40 + aseg * 8] = rb0;
        *(uint4*)&lB[buf][(arow + 64) * 40 + aseg * 8] = rb1;
    };

    f32x4 acc[4][2] = {};
    loadChunk(0);
    storeChunk(0);
    __syncthreads();

#pragma unroll
    for (int ks = 0; ks < 36; ++ks) {
        const int buf = ks & 1;
        if (ks < 35) loadChunk(ks + 1);
        short8 b0 = *(const short8*)&lB[buf][((wave * 2) * 16 + lrow) * 40 + quad * 8];
        short8 b1 = *(const short8*)&lB[buf][((wave * 2 + 1) * 16 + lrow) * 40 + quad * 8];
#pragma unroll
        for (int mi = 0; mi < 4; ++mi) {
            short8 a = *(const short8*)&lA[buf][(mi * 16 + lrow) * 40 + quad * 8];
            acc[mi][0] = MFMA(a, b0, acc[mi][0]);
            acc[mi][1] = MFMA(a, b1, acc[mi][1]);
        }
        if (ks < 35) storeChunk(buf ^ 1);
        __syncthreads();
    }

    if (mode == 0) {
        unsigned short* qn = qt + (size_t)n * PP * CH;
#pragma unroll
        for (int mi = 0; mi < 4; ++mi)
#pragma unroll
            for (int r = 0; r < 4; ++r) {
                int p = tile0 + mi * 16 + quad * 4 + r;
                if (p < PP)
#pragma unroll
                    for (int ni = 0; ni < 2; ++ni)
                        qn[(size_t)p * CH + (wave * 2 + ni) * 16 + lrow] = f2bf(acc[mi][ni][r]);
            }
    } else if (mode == 1) {
        unsigned short* kn = kt + (size_t)n * DD * CH;
#pragma unroll
        for (int mi = 0; mi < 4; ++mi)
#pragma unroll
            for (int r = 0; r < 4; ++r) {
                int d = tile0 + mi * 16 + quad * 4 + r;
                if (d < DD)
#pragma unroll
                    for (int ni = 0; ni < 2; ++ni)
                        kn[(size_t)d * CH + (wave * 2 + ni) * 16 + lrow] = f2bf(acc[mi][ni][r]);
            }
    } else {
        unsigned short* vn = vb + (size_t)n * CH * VP;
#pragma unroll
        for (int mi = 0; mi < 4; ++mi)
#pragma unroll
            for (int r = 0; r < 4; ++r) {
                int d = tile0 + mi * 16 + quad * 4 + r;
                if (d < DD)
#pragma unroll
                    for (int ni = 0; ni < 2; ++ni)
                        vn[(size_t)((wave * 2 + ni) * 16 + lrow) * VP + d] = f2bf(acc[mi][ni][r]);
            }
    }
}

// ---------------------------------------------------------------------------
// partial attention, LDS-staged — identical to round 13.
// ---------------------------------------------------------------------------
__global__ __launch_bounds__(256)
void k_attn(const unsigned short* __restrict__ qt, const unsigned short* __restrict__ kt,
            const unsigned short* __restrict__ vb, _Float16* __restrict__ po,
            float* __restrict__ pm, float* __restrict__ pl)
{
    __shared__ unsigned short lS[2][128 * 40];    // 2 x 10240 B chunk staging
    __shared__ unsigned short lp[4][16 * 136];    // per-wave P transpose
    const int t = threadIdx.x;
    const int wave = t >> 6, lane = t & 63;
    const int quad = lane >> 4, lrow = lane & 15;
    const int qg = blockIdx.x;
    const int dt = blockIdx.y;
    const int n = blockIdx.z;
    const int qti = qg * 4 + wave;                // may be >= QT (tail)
    const int d0 = dt * 128;
    const unsigned short* qn = qt + (size_t)n * PP * CH;
    const unsigned short* kn = kt + (size_t)n * DD * CH;
    const unsigned short* vn = vb + (size_t)n * CH * VP;

    const int arow = t >> 2, aseg8 = (t & 3) * 8;
    int kr0 = d0 + arow;      if (kr0 >= DD) kr0 = DD - 1;
    int kr1 = d0 + arow + 64; if (kr1 >= DD) kr1 = DD - 1;
    const unsigned short* kp0 = kn + (size_t)kr0 * CH + aseg8;
    const unsigned short* kp1 = kn + (size_t)kr1 * CH + aseg8;
    const unsigned short* vp0 = vn + (size_t)arow * VP + d0 + aseg8;
    const unsigned short* vp1 = vn + (size_t)(arow + 64) * VP + d0 + aseg8;
    const int lo0 = arow * 40 + aseg8;
    const int lo1 = (arow + 64) * 40 + aseg8;

    short8 qa[4];
    {
        int qrow = qti * 16 + lrow; if (qrow >= PP) qrow = PP - 1;
#pragma unroll
        for (int ks = 0; ks < 4; ++ks)
            qa[ks] = *(const short8*)&qn[(size_t)qrow * CH + ks * 32 + quad * 8];
    }

    // ---- S = Q.K^T, chunked over c, double-buffered ----
    f32x4 s[8] = {};
    uint4 r0 = *(const uint4*)kp0;
    uint4 r1 = *(const uint4*)kp1;
    *(uint4*)&lS[0][lo0] = r0;
    *(uint4*)&lS[0][lo1] = r1;
    __syncthreads();
#pragma unroll
    for (int ks = 0; ks < 4; ++ks) {
        const int buf = ks & 1;
        if (ks < 3) {
            r0 = *(const uint4*)(kp0 + (ks + 1) * 32);
            r1 = *(const uint4*)(kp1 + (ks + 1) * 32);
        }
#pragma unroll
        for (int ni = 0; ni < 8; ++ni) {
            short8 b = *(const short8*)&lS[buf][(ni * 16 + lrow) * 40 + quad * 8];
            s[ni] = MFMA(qa[ks], b, s[ni]);
        }
        if (ks < 3) {
            *(uint4*)&lS[buf ^ 1][lo0] = r0;
            *(uint4*)&lS[buf ^ 1][lo1] = r1;
        }
        __syncthreads();
    }

    // ---- tail mask + partial softmax (per wave) ----
#pragma unroll
    for (int ni = 0; ni < 8; ++ni)
        if (d0 + ni * 16 + lrow >= DD)
#pragma unroll
            for (int r = 0; r < 4; ++r) s[ni][r] = -1e30f;

    float mx[4] = {-1e30f, -1e30f, -1e30f, -1e30f};
#pragma unroll
    for (int ni = 0; ni < 8; ++ni)
#pragma unroll
        for (int r = 0; r < 4; ++r) mx[r] = fmaxf(mx[r], s[ni][r]);
#pragma unroll
    for (int off = 1; off < 16; off <<= 1)
#pragma unroll
        for (int r = 0; r < 4; ++r) mx[r] = fmaxf(mx[r], __shfl_xor(mx[r], off, 64));

    float rs[4] = {0.f, 0.f, 0.f, 0.f};
#pragma unroll
    for (int ni = 0; ni < 8; ++ni)
#pragma unroll
        for (int r = 0; r < 4; ++r) {
            float e = __expf(s[ni][r] - mx[r]);
            s[ni][r] = e;
            rs[r] += e;
        }
#pragma unroll
    for (int off = 1; off < 16; off <<= 1)
#pragma unroll
        for (int r = 0; r < 4; ++r) rs[r] += __shfl_xor(rs[r], off, 64);

    // P -> wave-private LDS (C-layout -> A-layout transpose)
#pragma unroll
    for (int ni = 0; ni < 8; ++ni)
#pragma unroll
        for (int r = 0; r < 4; ++r)
            lp[wave][(quad * 4 + r) * 136 + ni * 16 + lrow] = f2bf(s[ni][r]);

    // ---- O = P.V, chunked over d ----
    f32x4 o[8] = {};
    r0 = *(const uint4*)vp0;
    r1 = *(const uint4*)vp1;
    *(uint4*)&lS[0][lo0] = r0;
    *(uint4*)&lS[0][lo1] = r1;
    __syncthreads();
#pragma unroll
    for (int ks = 0; ks < 4; ++ks) {
        const int buf = ks & 1;
        if (ks < 3) {
            r0 = *(const uint4*)(vp0 + (ks + 1) * 32);
            r1 = *(const uint4*)(vp1 + (ks + 1) * 32);
        }
        short8 pa = *(const short8*)&lp[wave][lrow * 136 + ks * 32 + quad * 8];
#pragma unroll
        for (int ni = 0; ni < 8; ++ni) {
            short8 b = *(const short8*)&lS[buf][(ni * 16 + lrow) * 40 + quad * 8];
            o[ni] = MFMA(pa, b, o[ni]);
        }
        if (ks < 3) {
            *(uint4*)&lS[buf ^ 1][lo0] = r0;
            *(uint4*)&lS[buf ^ 1][lo1] = r1;
        }
        __syncthreads();
    }

    if (qti < QT) {
        const int base = (n * QT + qti) * DT + dt;
        _Float16* pob = po + (size_t)base * 2048;
#pragma unroll
        for (int ni = 0; ni < 8; ++ni)
#pragma unroll
            for (int r = 0; r < 4; ++r)
                pob[(quad * 4 + r) * 128 + ni * 16 + lrow] = (_Float16)o[ni][r];
        if (lrow == 0)
#pragma unroll
            for (int r = 0; r < 4; ++r) {
                pm[base * 16 + quad * 4 + r] = mx[r];
                pl[base * 16 + quad * 4 + r] = rs[r];
            }
    }
}

// ---------------------------------------------------------------------------
// fused attention-reduce + h + out: literal concatenation of round-13's
// k_ared and k_hout, with the merged a0 tile kept in LDS (la0) instead of a
// global round-trip. Grid (81, 8), 256 threads; all barriers block-uniform.
// ---------------------------------------------------------------------------
__global__ __launch_bounds__(256)
void k_ahout(const _Float16* __restrict__ po, const float* __restrict__ pm,
             const float* __restrict__ pl, const unsigned short* __restrict__ xt,
             const unsigned short* __restrict__ whb, const float* __restrict__ hconst,
             const unsigned short* __restrict__ wob, const float* __restrict__ bo,
             float* __restrict__ out)
{
    __shared__ float sm[160], ssc[160], smg[16], sli[16];
    __shared__ unsigned short la0[16 * 136];
    __shared__ unsigned short lh[16 * 136];
    const int qti = blockIdx.x;
    const int n = blockIdx.y;
    const int base = (n * QT + qti) * DT;
    const int t = threadIdx.x;

    // ---- phase 1: merge the 10 d-tile partials -> la0[16q x 128c] ----
    if (t < 160) sm[t] = pm[base * 16 + t];
    __syncthreads();
    if (t < 16) {
        float mg = -1e30f;
#pragma unroll
        for (int dt = 0; dt < DT; ++dt) mg = fmaxf(mg, sm[dt * 16 + t]);
        float ls = 0.f;
#pragma unroll
        for (int dt = 0; dt < DT; ++dt) ls += __expf(sm[dt * 16 + t] - mg) * pl[base * 16 + dt * 16 + t];
        smg[t] = mg; sli[t] = 1.f / ls;
    }
    __syncthreads();
    if (t < 160) ssc[t] = __expf(sm[t] - smg[t & 15]);
    __syncthreads();
#pragma unroll
    for (int k = 0; k < 8; ++k) {
        int idx = t + k * 256;
        int row = idx >> 7, c = idx & 127;
        float acc = 0.f;
#pragma unroll
        for (int dt = 0; dt < DT; ++dt)
            acc += ssc[dt * 16 + row] * (float)po[(size_t)(base + dt) * 2048 + idx];
        la0[row * 136 + c] = f2bf(acc * sli[row]);
    }
    __syncthreads();

    // ---- phase 2: h = tanh(whb.[x;a0]+hconst) -> lh -> out = wob.h+b_o ----
    const int wave = t >> 6, lane = t & 63;
    const int quad = lane >> 4, lrow = lane & 15;
    const int p0 = qti * 16;
    const unsigned short* x0 = xt + (size_t)n * PP * CH;

    f32x4 acc1[2] = {};
#pragma unroll
    for (int ks = 0; ks < 8; ++ks) {
        int col = (ks & 3) * 32 + quad * 8;
        short8 a;
        if (ks < 4) a = *(const short8*)&x0[(size_t)(p0 + lrow) * CH + col];
        else        a = *(const short8*)&la0[lrow * 136 + col];
#pragma unroll
        for (int j = 0; j < 2; ++j) {
            int ni = wave * 2 + j;
            short8 b = *(const short8*)&whb[(size_t)(ni * 16 + lrow) * 256 + ks * 32 + quad * 8];
            acc1[j] = MFMA(a, b, acc1[j]);
        }
    }
#pragma unroll
    for (int j = 0; j < 2; ++j) {
        int ni = wave * 2 + j;
        float hc = hconst[ni * 16 + lrow];
#pragma unroll
        for (int r = 0; r < 4; ++r)
            lh[(quad * 4 + r) * 136 + ni * 16 + lrow] = f2bf(fast_tanh(acc1[j][r] + hc));
    }
    __syncthreads();

    f32x4 acc2[2] = {};
#pragma unroll
    for (int ks = 0; ks < 4; ++ks) {
        short8 a = *(const short8*)&lh[lrow * 136 + ks * 32 + quad * 8];
#pragma unroll
        for (int j = 0; j < 2; ++j) {
            int ni = wave * 2 + j;
            short8 b = *(const short8*)&wob[(size_t)(ni * 16 + lrow) * CH + ks * 32 + quad * 8];
            acc2[j] = MFMA(a, b, acc2[j]);
        }
    }
#pragma unroll
    for (int j = 0; j < 2; ++j) {
        int ni = wave * 2 + j;
        float bv = bo[ni * 16 + lrow];
#pragma unroll
        for (int r = 0; r < 4; ++r)
            out[((size_t)(n * CH + ni * 16 + lrow)) * PP + p0 + quad * 4 + r] = acc2[j][r] + bv;
    }
}

// ---------------------------------------------------------------------------
extern "C" void kernel_launch(void* const* d_in, const int* in_sizes, int n_in,
                              void* d_out, int out_size, void* d_ws, size_t ws_size,
                              hipStream_t stream)
{
    const float* inp  = (const float*)d_in[0];
    const float* c0   = (const float*)d_in[1];
    const float* w_x  = (const float*)d_in[2];
    const float* b_x  = (const float*)d_in[3];
    const float* w_qx = (const float*)d_in[4];
    const float* w_kx = (const float*)d_in[6];
    const float* w_vx = (const float*)d_in[8];
    const float* w_vc = (const float*)d_in[9];
    const float* w_h  = (const float*)d_in[14];
    const float* b_h  = (const float*)d_in[15];
    const float* w_o  = (const float*)d_in[16];
    const float* b_o  = (const float*)d_in[17];
    float* out = (float*)d_out;

    char* w = (char*)d_ws;
    unsigned short* xt   = (unsigned short*)(w);             // 2,654,208
    unsigned short* qt   = (unsigned short*)(w + 2654208);   // 2,654,208
    unsigned short* kt   = (unsigned short*)(w + 5308416);   // 2,367,488
    unsigned short* vb   = (unsigned short*)(w + 7675904);   // 2,621,440
    unsigned short* wcat = (unsigned short*)(w + 12951552);  // 884,736
    unsigned short* wxb  = (unsigned short*)(w + 13836288);  // 32,768
    unsigned short* whb  = (unsigned short*)(w + 13869056);  // 65,536
    unsigned short* wob  = (unsigned short*)(w + 13934592);  // 32,768
    float* hconst        = (float*)(w + 13967360);           // 512
    float* pm            = (float*)(w + 13967872);           // 414,720
    float* pl            = (float*)(w + 14382592);           // 414,720
    _Float16* po         = (_Float16*)(w + 14797312);        // 26,542,080 -> 41.3 MB total

    hipLaunchKernelGGL(k_setup, dim3(577), dim3(256), 0, stream,
                       w_qx, w_kx, w_vx, w_h, w_o, w_x, c0, w_vc, b_h,
                       wcat, whb, wob, wxb, hconst);

    hipLaunchKernelGGL(k_proj, dim3(QT, 2, NN), dim3(64), 0, stream, inp, wxb, b_x, xt);

    hipLaunchKernelGGL(k_conv, dim3(21, 3, NN), dim3(256), 0, stream, xt, wcat, qt, kt, vb);

    hipLaunchKernelGGL(k_attn, dim3(21, DT, NN), dim3(256), 0, stream, qt, kt, vb, po, pm, pl);

    hipLaunchKernelGGL(k_ahout, dim3(QT, NN), dim3(256), 0, stream,
                       po, pm, pl, xt, whb, hconst, wob, b_o, out);
}